// Round 2
// baseline (388.950 us; speedup 1.0000x reference)
//
#include <hip/hip_runtime.h>

#define Bsz 1024
#define Nn 256
#define Fdim 8
#define Eedge 1024
#define OUTC 128
#define CADV 192
#define CTOT 256

// ---------------------------------------------------------------------------
// Kernel A: edge-MLP theta (identical for all edges since edge_attr==1),
// scatter S[t] = sum of x[0, src, :] over edges targeting t, msg = S @ theta.
// edge_index arrives as int32 per harness contract ("integer -> const int*");
// runtime-detect little-endian int64 as a fallback (odd int32 slots all 0).
// ---------------------------------------------------------------------------
__global__ __launch_bounds__(256) void setup_kernel(
    const float* __restrict__ x, const int* __restrict__ ei,
    const float* __restrict__ w1, const float* __restrict__ b1,
    const float* __restrict__ w2, const float* __restrict__ b2,
    float* __restrict__ msg)
{
  __shared__ float h_s[64];
  __shared__ float theta_s[1024];
  __shared__ float S_s[Nn * Fdim];
  __shared__ int is64_s;
  int t = threadIdx.x;
  if (t < 64) h_s[t] = fmaxf(w1[t] + b1[t], 0.f);
  for (int i = t; i < Nn * Fdim; i += 256) S_s[i] = 0.f;
  if (t == 0) {
    int z = 0;
    for (int i = 1; i < 16; i += 2) z |= ei[i];
    is64_s = (z == 0);  // int64 little-endian: high words are all zero
  }
  __syncthreads();
  int is64 = is64_s;
  // theta[c] = sum_j h[j] * w2[j,c] + b2[c]   (c = f*128 + o)
  for (int i = 0; i < 4; ++i) {
    int c = t + i * 256;
    float acc = b2[c];
#pragma unroll
    for (int j = 0; j < 64; ++j) acc += h_s[j] * w2[j * 1024 + c];
    theta_s[c] = acc;
  }
  // scatter: S[tgt] += x[0, src, :]
  for (int e = t; e < Eedge; e += 256) {
    int src, tgt;
    if (is64) { src = ei[2 * e];            tgt = ei[2 * (Eedge + e)]; }
    else      { src = ei[e];                tgt = ei[Eedge + e]; }
    src &= 255; tgt &= 255;  // defensive: never corrupt LDS
#pragma unroll
    for (int f = 0; f < Fdim; ++f)
      atomicAdd(&S_s[tgt * Fdim + f], x[src * Fdim + f]);
  }
  __syncthreads();
  // msg[n,o] = sum_f S[n,f] * theta[f,o]
  for (int i = 0; i < 128; ++i) {
    int idx = i * 256 + t;
    int n = idx >> 7, o = idx & 127;
    float m = 0.f;
#pragma unroll
    for (int f = 0; f < Fdim; ++f) m += S_s[n * Fdim + f] * theta_s[f * 128 + o];
    msg[idx] = m;
  }
}

// ---------------------------------------------------------------------------
// Kernel B: fused feat-construction + GEMM.
//   feat[b, n*128+o] = relu(x[b,n,:]@root_w[:,o] + conv_b[o] + (b==0)*msg[n,o])
//   partial[kc][b][c] = sum over this block's K-range of feat * W[:,c]
//   where W = [adv_w | v1w] (256 cols).
// Grid: (8 M-tiles of BM=128) x NS K-chunks. 256 threads, per-thread 8x16 tile.
// ---------------------------------------------------------------------------
#define BM 128
#define KB 32
#define FROW 192   // feat LDS row: 16 groups * (8 + 4 pad) floats -> 2-way only

__global__ __launch_bounds__(256, 2) void gemm_kernel(
    const float* __restrict__ x, const float* __restrict__ rootw,
    const float* __restrict__ convb, const float* __restrict__ advw,
    const float* __restrict__ v1w, const float* __restrict__ msg,
    float* __restrict__ part, int npc)
{
  __shared__ float w_s[KB * CTOT];     // 32 KB
  __shared__ float f_s[KB * FROW];     // 24 KB
  __shared__ float rw_s[Fdim * OUTC];  // 4 KB
  __shared__ float cb_s[OUTC];

  int t = threadIdx.x;
  int m0 = blockIdx.x * BM;
  int n0 = blockIdx.y * npc;

  for (int i = t; i < Fdim * OUTC; i += 256) rw_s[i] = rootw[i];
  if (t < OUTC) cb_s[t] = convb[t];

  float acc[8][16];
#pragma unroll
  for (int r = 0; r < 8; ++r)
#pragma unroll
    for (int c = 0; c < 16; ++c) acc[r][c] = 0.f;

  int rr = t & 127;   // feat-staging row
  int ohalf = t >> 7; // which 16-wide o half
  int brow = m0 + rr;
  bool isb0 = (brow == 0);
  int tm = t & 15;    // 16 row-groups of 8
  int tn = t >> 4;    // 16 col-groups of 16

  for (int nn = 0; nn < npc; ++nn) {
    int node = n0 + nn;
    const float* xp = x + ((size_t)brow * Nn + node) * Fdim;
    float4 xa = *(const float4*)(xp);
    float4 xb = *(const float4*)(xp + 4);
    const float* msgrow = msg + node * OUTC;

    for (int ob = 0; ob < 4; ++ob) {
      int kbase = node * OUTC + ob * KB;
      __syncthreads();  // previous tile fully consumed (also covers rw_s/cb_s)
      // ---- stage W tile: 32 rows x 256 cols = 2048 float4 slots ----
#pragma unroll
      for (int i = 0; i < 8; ++i) {
        int slot = i * 256 + t;
        int k = slot >> 6;
        int j = slot & 63;  // float4 index within row
        int krow = kbase + k;
        float4 v;
        if (j < 48) v = *(const float4*)(advw + (size_t)krow * CADV + j * 4);
        else        v = *(const float4*)(v1w + (size_t)krow * 64 + (j - 48) * 4);
        *(float4*)(w_s + k * CTOT + j * 4) = v;
      }
      // ---- stage feat tile: 32 o x 128 rows ----
      int obase = ob * KB + ohalf * 16;
#pragma unroll
      for (int j = 0; j < 16; ++j) {
        int o = obase + j;
        float v = cb_s[o];
        v += xa.x * rw_s[0 * OUTC + o] + xa.y * rw_s[1 * OUTC + o] +
             xa.z * rw_s[2 * OUTC + o] + xa.w * rw_s[3 * OUTC + o];
        v += xb.x * rw_s[4 * OUTC + o] + xb.y * rw_s[5 * OUTC + o] +
             xb.z * rw_s[6 * OUTC + o] + xb.w * rw_s[7 * OUTC + o];
        if (isb0) v += msgrow[o];
        v = fmaxf(v, 0.f);
        int kl = o - ob * KB;  // 0..31
        f_s[kl * FROW + (rr >> 3) * 12 + (rr & 7)] = v;
      }
      __syncthreads();
      // ---- GEMM: 32 k-steps, per-thread 8x16 ----
#pragma unroll 2
      for (int k = 0; k < KB; ++k) {
        float4 a0 = *(const float4*)(f_s + k * FROW + tm * 12);
        float4 a1 = *(const float4*)(f_s + k * FROW + tm * 12 + 4);
        float4 w0 = *(const float4*)(w_s + k * CTOT + tn * 16);
        float4 w1v = *(const float4*)(w_s + k * CTOT + tn * 16 + 4);
        float4 w2v = *(const float4*)(w_s + k * CTOT + tn * 16 + 8);
        float4 w3v = *(const float4*)(w_s + k * CTOT + tn * 16 + 12);
        float av[8] = {a0.x, a0.y, a0.z, a0.w, a1.x, a1.y, a1.z, a1.w};
        float wv[16] = {w0.x,  w0.y,  w0.z,  w0.w,  w1v.x, w1v.y, w1v.z, w1v.w,
                        w2v.x, w2v.y, w2v.z, w2v.w, w3v.x, w3v.y, w3v.z, w3v.w};
#pragma unroll
        for (int r = 0; r < 8; ++r)
#pragma unroll
          for (int c = 0; c < 16; ++c) acc[r][c] += av[r] * wv[c];
      }
    }
  }
  // ---- write partials: part[kc][row][col] ----
  float* pb = part + ((size_t)blockIdx.y * Bsz + m0) * CTOT;
#pragma unroll
  for (int r = 0; r < 8; ++r) {
    int row = tm * 8 + r;
#pragma unroll
    for (int c4 = 0; c4 < 4; ++c4) {
      float4 v = make_float4(acc[r][c4 * 4 + 0], acc[r][c4 * 4 + 1],
                             acc[r][c4 * 4 + 2], acc[r][c4 * 4 + 3]);
      *(float4*)(pb + (size_t)row * CTOT + tn * 16 + c4 * 4) = v;
    }
  }
}

// ---------------------------------------------------------------------------
// Kernel C: reduce K-partials, apply biases+relu, val MLP chain, dueling head.
// One block per batch row, 256 threads (one per fused column).
// ---------------------------------------------------------------------------
__global__ __launch_bounds__(256) void final_kernel(
    const float* __restrict__ part, int ns,
    const float* __restrict__ advb, const float* __restrict__ v1b,
    const float* __restrict__ v2w, const float* __restrict__ v2b,
    const float* __restrict__ v3w, const float* __restrict__ v3b,
    float* __restrict__ out)
{
  __shared__ float adv_s[CADV];
  __shared__ float v1_s[64];
  __shared__ float val2_s[64];
  __shared__ float val3_s[64];
  int b = blockIdx.x, t = threadIdx.x;
  float s = 0.f;
  const float* p = part + (size_t)b * CTOT + t;
  for (int i = 0; i < ns; ++i) s += p[(size_t)i * Bsz * CTOT];
  if (t < CADV) adv_s[t] = fmaxf(s + advb[t], 0.f);
  else          v1_s[t - CADV] = fmaxf(s + v1b[t - CADV], 0.f);
  __syncthreads();
  if (t < 64) {
    float a = v2b[t];
#pragma unroll
    for (int i = 0; i < 64; ++i) a += v1_s[i] * v2w[i * 64 + t];
    val2_s[t] = fmaxf(a, 0.f);
  }
  __syncthreads();
  if (t < 64) {
    float a = v3b[t];
#pragma unroll
    for (int j = 0; j < 64; ++j) a += val2_s[j] * v3w[j * 64 + t];
    val3_s[t] = a;
  }
  __syncthreads();
  if (t < CADV) {
    int d = t / 3;
    float mean = (adv_s[d * 3] + adv_s[d * 3 + 1] + adv_s[d * 3 + 2]) * (1.f / 3.f);
    out[(size_t)b * CADV + t] = val3_s[d] + adv_s[t] - mean;
  }
}

extern "C" void kernel_launch(void* const* d_in, const int* in_sizes, int n_in,
                              void* d_out, int out_size, void* d_ws, size_t ws_size,
                              hipStream_t stream)
{
  (void)in_sizes; (void)n_in; (void)out_size;
  const float* x     = (const float*)d_in[0];
  const int*   ei    = (const int*)d_in[1];     // int32 per harness contract
  const float* w1    = (const float*)d_in[2];
  const float* b1    = (const float*)d_in[3];
  const float* w2    = (const float*)d_in[4];
  const float* b2    = (const float*)d_in[5];
  const float* rootw = (const float*)d_in[6];
  const float* convb = (const float*)d_in[7];
  const float* advw  = (const float*)d_in[8];
  const float* advb  = (const float*)d_in[9];
  const float* v1w   = (const float*)d_in[10];
  const float* v1b   = (const float*)d_in[11];
  const float* v2w   = (const float*)d_in[12];
  const float* v2b   = (const float*)d_in[13];
  const float* v3w   = (const float*)d_in[14];
  const float* v3b   = (const float*)d_in[15];
  float* out = (float*)d_out;

  float* msg = (float*)d_ws;                 // 32768 floats
  // K-split count: 64 preferred (2048 waves -> 2/SIMD); shrink if ws too small.
  int NS = 64;
  while (NS > 1 && (size_t)(32768 + (size_t)NS * Bsz * CTOT) * 4 > ws_size) NS >>= 1;
  float* part = msg + 32768;
  int npc = Nn / NS;  // nodes per K-chunk

  setup_kernel<<<1, 256, 0, stream>>>(x, ei, w1, b1, w2, b2, msg);
  dim3 grid(Bsz / BM, NS);
  gemm_kernel<<<grid, 256, 0, stream>>>(x, rootw, convb, advw, v1w, msg, part, npc);
  final_kernel<<<Bsz, 256, 0, stream>>>(part, NS, advb, v1b, v2w, v2b, v3w, v3b, out);
}

// Round 3
// 230.775 us; speedup vs baseline: 1.6854x; 1.6854x over previous
//
#include <hip/hip_runtime.h>

#define Bsz 1024
#define Nn 256
#define Fdim 8
#define Eedge 1024
#define OUTC 128
#define CADV 192
#define CTOT 256
#define Ktot 32768   // Nn * OUTC
#define ASTR 40      // LDS row stride in bf16 (32 + 8 pad): 2-way banks only

typedef __attribute__((ext_vector_type(8))) short short8;
typedef __attribute__((ext_vector_type(4))) float float4v;

static __device__ inline unsigned short f2bf(float f) {
  union { float f; unsigned u; } v; v.f = f;
  unsigned r = v.u + 0x7FFFu + ((v.u >> 16) & 1u);  // round-nearest-even
  return (unsigned short)(r >> 16);
}
static __device__ inline uint4 pack8(const unsigned short* b) {
  uint4 v;
  v.x = (unsigned)b[0] | ((unsigned)b[1] << 16);
  v.y = (unsigned)b[2] | ((unsigned)b[3] << 16);
  v.z = (unsigned)b[4] | ((unsigned)b[5] << 16);
  v.w = (unsigned)b[6] | ((unsigned)b[7] << 16);
  return v;
}

// ---------------------------------------------------------------------------
// Kernel A: theta (edge MLP, identical per edge), scatter S, msg = S @ theta.
// ---------------------------------------------------------------------------
__global__ __launch_bounds__(256) void setup_kernel(
    const float* __restrict__ x, const int* __restrict__ ei,
    const float* __restrict__ w1, const float* __restrict__ b1,
    const float* __restrict__ w2, const float* __restrict__ b2,
    float* __restrict__ msg)
{
  __shared__ float h_s[64];
  __shared__ float theta_s[1024];
  __shared__ float S_s[Nn * Fdim];
  __shared__ int is64_s;
  int t = threadIdx.x;
  if (t < 64) h_s[t] = fmaxf(w1[t] + b1[t], 0.f);
  for (int i = t; i < Nn * Fdim; i += 256) S_s[i] = 0.f;
  if (t == 0) {
    int z = 0;
    for (int i = 1; i < 16; i += 2) z |= ei[i];
    is64_s = (z == 0);
  }
  __syncthreads();
  int is64 = is64_s;
  for (int i = 0; i < 4; ++i) {
    int c = t + i * 256;
    float acc = b2[c];
#pragma unroll
    for (int j = 0; j < 64; ++j) acc += h_s[j] * w2[j * 1024 + c];
    theta_s[c] = acc;
  }
  for (int e = t; e < Eedge; e += 256) {
    int src, tgt;
    if (is64) { src = ei[2 * e]; tgt = ei[2 * (Eedge + e)]; }
    else      { src = ei[e];     tgt = ei[Eedge + e]; }
    src &= 255; tgt &= 255;
#pragma unroll
    for (int f = 0; f < Fdim; ++f)
      atomicAdd(&S_s[tgt * Fdim + f], x[src * Fdim + f]);
  }
  __syncthreads();
  for (int i = 0; i < 128; ++i) {
    int idx = i * 256 + t;
    int n = idx >> 7, o = idx & 127;
    float m = 0.f;
#pragma unroll
    for (int f = 0; f < Fdim; ++f) m += S_s[n * Fdim + f] * theta_s[f * 128 + o];
    msg[idx] = m;
  }
}

// ---------------------------------------------------------------------------
// Prep: Wt[kt][c][32] bf16, kt = k>>5.  W[k][c] = c<192 ? advw : v1w.
// ---------------------------------------------------------------------------
__global__ __launch_bounds__(256) void wt_kernel(
    const float* __restrict__ advw, const float* __restrict__ v1w,
    unsigned short* __restrict__ wt)
{
  int kt = blockIdx.x;   // 0..1023
  int c = threadIdx.x;   // 0..255
  const float* src; int stride, col;
  if (c < CADV) { src = advw; stride = CADV; col = c; }
  else          { src = v1w;  stride = 64;   col = c - CADV; }
  unsigned short buf[32];
#pragma unroll
  for (int i = 0; i < 32; ++i)
    buf[i] = f2bf(src[(size_t)(kt * 32 + i) * stride + col]);
  uint4* dst = (uint4*)(wt + ((size_t)kt * CTOT + c) * 32);
#pragma unroll
  for (int p = 0; p < 4; ++p) dst[p] = pack8(buf + p * 8);
}

// ---------------------------------------------------------------------------
// Prep: feat bf16, layout feat[kt][b][32] (kt = (n*128+o)>>5), ready for
// direct lane-linear A-tile staging in the MFMA GEMM.
// ---------------------------------------------------------------------------
__global__ __launch_bounds__(256) void feat_kernel(
    const float* __restrict__ x, const float* __restrict__ rootw,
    const float* __restrict__ convb, const float* __restrict__ msg,
    unsigned short* __restrict__ feat)
{
  __shared__ float rw_s[Fdim * OUTC];
  __shared__ float cb_s[OUTC];
  int n = blockIdx.x;      // node
  int by = blockIdx.y;     // batch chunk of 128
  int t = threadIdx.x;
  for (int i = t; i < Fdim * OUTC; i += 256) rw_s[i] = rootw[i];
  if (t < OUTC) cb_s[t] = convb[t];
  __syncthreads();
  int b = by * 128 + (t & 127);
  int oh = t >> 7;         // 0/1 -> o range of 64
  const float* xp = x + ((size_t)b * Nn + n) * Fdim;
  float xr[8];
#pragma unroll
  for (int f = 0; f < Fdim; ++f) xr[f] = xp[f];
  bool isb0 = (b == 0);
  const float* msgrow = msg + n * OUTC;
  for (int r = 0; r < 2; ++r) {
    int obase = oh * 64 + r * 32;
    unsigned short buf[32];
#pragma unroll
    for (int j = 0; j < 32; ++j) {
      int o = obase + j;
      float v = cb_s[o];
#pragma unroll
      for (int f = 0; f < Fdim; ++f) v += xr[f] * rw_s[f * OUTC + o];
      if (isb0) v += msgrow[o];
      buf[j] = f2bf(fmaxf(v, 0.f));
    }
    int kt = n * 4 + oh * 2 + r;
    uint4* dst = (uint4*)(feat + ((size_t)kt * Bsz + b) * 32);
#pragma unroll
    for (int p = 0; p < 4; ++p) dst[p] = pack8(buf + p * 8);
  }
}

// ---------------------------------------------------------------------------
// MFMA GEMM: part[ch][m][c] = feat[m, kchunk] @ W[kchunk, c].
// Block: 512 thr = 8 waves, tile 256m x 256c. Wave: 64m x 128c = 4x8 MFMA
// tiles (16x16x32 bf16). Grid (4 m-blocks, NS chunks).
// ---------------------------------------------------------------------------
__global__ __launch_bounds__(512, 2) void gemm_mfma(
    const unsigned short* __restrict__ feat, const unsigned short* __restrict__ wt,
    float* __restrict__ part, int iters)
{
  __shared__ short a_s[256 * ASTR];   // 20 KB
  __shared__ short b_s[256 * ASTR];   // 20 KB
  int t = threadIdx.x;
  int mb = blockIdx.x;   // 0..3
  int ch = blockIdx.y;   // K chunk
  int wave = t >> 6, lane = t & 63;
  int wm = wave >> 1, wn = wave & 1;
  int lm = lane & 15, lq = lane >> 4;

  float4v acc[4][8];
#pragma unroll
  for (int i = 0; i < 4; ++i)
#pragma unroll
    for (int j = 0; j < 8; ++j) acc[i][j] = (float4v)0.f;

  // staging: 16KB A-slab + 16KB B-slab = 2048 x 16B units; 4 units/thread
  int u0 = t, u1 = t + 512;
  int br0 = u0 >> 2, bq0 = u0 & 3, br1 = u1 >> 2, bq1 = u1 & 3;

  // precompute frag LDS offsets (elements)
  int aoff[4], boff[8];
#pragma unroll
  for (int i = 0; i < 4; ++i) aoff[i] = (wm * 64 + i * 16 + lm) * ASTR + lq * 8;
#pragma unroll
  for (int j = 0; j < 8; ++j) boff[j] = (wn * 128 + j * 16 + lm) * ASTR + lq * 8;

  for (int kk = 0; kk < iters; ++kk) {
    int kt = ch * iters + kk;
    const uint4* gB = (const uint4*)(wt + (size_t)kt * (CTOT * 32));
    const uint4* gA = (const uint4*)(feat + ((size_t)kt * Bsz + mb * 256) * 32);
    uint4 vb0 = gB[u0], vb1 = gB[u1];
    uint4 va0 = gA[u0], va1 = gA[u1];
    __syncthreads();  // previous tile fully consumed
    *(uint4*)(b_s + br0 * ASTR + bq0 * 8) = vb0;
    *(uint4*)(b_s + br1 * ASTR + bq1 * 8) = vb1;
    *(uint4*)(a_s + br0 * ASTR + bq0 * 8) = va0;
    *(uint4*)(a_s + br1 * ASTR + bq1 * 8) = va1;
    __syncthreads();
    short8 aF[4], bF[8];
#pragma unroll
    for (int i = 0; i < 4; ++i) aF[i] = *(const short8*)(a_s + aoff[i]);
#pragma unroll
    for (int j = 0; j < 8; ++j) bF[j] = *(const short8*)(b_s + boff[j]);
#pragma unroll
    for (int i = 0; i < 4; ++i)
#pragma unroll
      for (int j = 0; j < 8; ++j)
        acc[i][j] = __builtin_amdgcn_mfma_f32_16x16x32_bf16(aF[i], bF[j], acc[i][j], 0, 0, 0);
  }

  float* pb = part + ((size_t)ch * Bsz + mb * 256) * CTOT;
#pragma unroll
  for (int i = 0; i < 4; ++i)
#pragma unroll
    for (int r = 0; r < 4; ++r) {
      int m = wm * 64 + i * 16 + lq * 4 + r;
#pragma unroll
      for (int j = 0; j < 8; ++j) {
        int c = wn * 128 + j * 16 + lm;
        pb[(size_t)m * CTOT + c] = acc[i][j][r];
      }
    }
}

// ---------------------------------------------------------------------------
// Fallback fp32 GEMM (R2 kernel, known-correct) for small ws.
// ---------------------------------------------------------------------------
#define BM 128
#define KB 32
#define FROW 192

__global__ __launch_bounds__(256, 2) void gemm_f32(
    const float* __restrict__ x, const float* __restrict__ rootw,
    const float* __restrict__ convb, const float* __restrict__ advw,
    const float* __restrict__ v1w, const float* __restrict__ msg,
    float* __restrict__ part, int npc)
{
  __shared__ float w_s[KB * CTOT];
  __shared__ float f_s[KB * FROW];
  __shared__ float rw_s[Fdim * OUTC];
  __shared__ float cb_s[OUTC];
  int t = threadIdx.x;
  int m0 = blockIdx.x * BM;
  int n0 = blockIdx.y * npc;
  for (int i = t; i < Fdim * OUTC; i += 256) rw_s[i] = rootw[i];
  if (t < OUTC) cb_s[t] = convb[t];
  float acc[8][16];
#pragma unroll
  for (int r = 0; r < 8; ++r)
#pragma unroll
    for (int c = 0; c < 16; ++c) acc[r][c] = 0.f;
  int rr = t & 127, ohalf = t >> 7;
  int brow = m0 + rr;
  bool isb0 = (brow == 0);
  int tm = t & 15, tn = t >> 4;
  for (int nn = 0; nn < npc; ++nn) {
    int node = n0 + nn;
    const float* xp = x + ((size_t)brow * Nn + node) * Fdim;
    float4 xa = *(const float4*)(xp);
    float4 xb = *(const float4*)(xp + 4);
    const float* msgrow = msg + node * OUTC;
    for (int ob = 0; ob < 4; ++ob) {
      int kbase = node * OUTC + ob * KB;
      __syncthreads();
#pragma unroll
      for (int i = 0; i < 8; ++i) {
        int slot = i * 256 + t;
        int k = slot >> 6, j = slot & 63;
        int krow = kbase + k;
        float4 v;
        if (j < 48) v = *(const float4*)(advw + (size_t)krow * CADV + j * 4);
        else        v = *(const float4*)(v1w + (size_t)krow * 64 + (j - 48) * 4);
        *(float4*)(w_s + k * CTOT + j * 4) = v;
      }
      int obase = ob * KB + ohalf * 16;
#pragma unroll
      for (int j = 0; j < 16; ++j) {
        int o = obase + j;
        float v = cb_s[o];
        v += xa.x * rw_s[0 * OUTC + o] + xa.y * rw_s[1 * OUTC + o] +
             xa.z * rw_s[2 * OUTC + o] + xa.w * rw_s[3 * OUTC + o];
        v += xb.x * rw_s[4 * OUTC + o] + xb.y * rw_s[5 * OUTC + o] +
             xb.z * rw_s[6 * OUTC + o] + xb.w * rw_s[7 * OUTC + o];
        if (isb0) v += msgrow[o];
        v = fmaxf(v, 0.f);
        int kl = o - ob * KB;
        f_s[kl * FROW + (rr >> 3) * 12 + (rr & 7)] = v;
      }
      __syncthreads();
#pragma unroll 2
      for (int k = 0; k < KB; ++k) {
        float4 a0 = *(const float4*)(f_s + k * FROW + tm * 12);
        float4 a1 = *(const float4*)(f_s + k * FROW + tm * 12 + 4);
        float4 w0 = *(const float4*)(w_s + k * CTOT + tn * 16);
        float4 w1v = *(const float4*)(w_s + k * CTOT + tn * 16 + 4);
        float4 w2v = *(const float4*)(w_s + k * CTOT + tn * 16 + 8);
        float4 w3v = *(const float4*)(w_s + k * CTOT + tn * 16 + 12);
        float av[8] = {a0.x, a0.y, a0.z, a0.w, a1.x, a1.y, a1.z, a1.w};
        float wv[16] = {w0.x,  w0.y,  w0.z,  w0.w,  w1v.x, w1v.y, w1v.z, w1v.w,
                        w2v.x, w2v.y, w2v.z, w2v.w, w3v.x, w3v.y, w3v.z, w3v.w};
#pragma unroll
        for (int r = 0; r < 8; ++r)
#pragma unroll
          for (int c = 0; c < 16; ++c) acc[r][c] += av[r] * wv[c];
      }
    }
  }
  float* pb = part + ((size_t)blockIdx.y * Bsz + m0) * CTOT;
#pragma unroll
  for (int r = 0; r < 8; ++r) {
    int row = tm * 8 + r;
#pragma unroll
    for (int c4 = 0; c4 < 4; ++c4) {
      float4 v = make_float4(acc[r][c4 * 4 + 0], acc[r][c4 * 4 + 1],
                             acc[r][c4 * 4 + 2], acc[r][c4 * 4 + 3]);
      *(float4*)(pb + (size_t)row * CTOT + tn * 16 + c4 * 4) = v;
    }
  }
}

// ---------------------------------------------------------------------------
// Final: reduce split-K partials, biases+relu, val MLP, dueling combine.
// ---------------------------------------------------------------------------
__global__ __launch_bounds__(256) void final_kernel(
    const float* __restrict__ part, int ns,
    const float* __restrict__ advb, const float* __restrict__ v1b,
    const float* __restrict__ v2w, const float* __restrict__ v2b,
    const float* __restrict__ v3w, const float* __restrict__ v3b,
    float* __restrict__ out)
{
  __shared__ float adv_s[CADV];
  __shared__ float v1_s[64];
  __shared__ float val2_s[64];
  __shared__ float val3_s[64];
  int b = blockIdx.x, t = threadIdx.x;
  float s = 0.f;
  const float* p = part + (size_t)b * CTOT + t;
  for (int i = 0; i < ns; ++i) s += p[(size_t)i * Bsz * CTOT];
  if (t < CADV) adv_s[t] = fmaxf(s + advb[t], 0.f);
  else          v1_s[t - CADV] = fmaxf(s + v1b[t - CADV], 0.f);
  __syncthreads();
  if (t < 64) {
    float a = v2b[t];
#pragma unroll
    for (int i = 0; i < 64; ++i) a += v1_s[i] * v2w[i * 64 + t];
    val2_s[t] = fmaxf(a, 0.f);
  }
  __syncthreads();
  if (t < 64) {
    float a = v3b[t];
#pragma unroll
    for (int j = 0; j < 64; ++j) a += val2_s[j] * v3w[j * 64 + t];
    val3_s[t] = a;
  }
  __syncthreads();
  if (t < CADV) {
    int d = t / 3;
    float mean = (adv_s[d * 3] + adv_s[d * 3 + 1] + adv_s[d * 3 + 2]) * (1.f / 3.f);
    out[(size_t)b * CADV + t] = val3_s[d] + adv_s[t] - mean;
  }
}

extern "C" void kernel_launch(void* const* d_in, const int* in_sizes, int n_in,
                              void* d_out, int out_size, void* d_ws, size_t ws_size,
                              hipStream_t stream)
{
  (void)in_sizes; (void)n_in; (void)out_size;
  const float* x     = (const float*)d_in[0];
  const int*   ei    = (const int*)d_in[1];
  const float* w1    = (const float*)d_in[2];
  const float* b1    = (const float*)d_in[3];
  const float* w2    = (const float*)d_in[4];
  const float* b2    = (const float*)d_in[5];
  const float* rootw = (const float*)d_in[6];
  const float* convb = (const float*)d_in[7];
  const float* advw  = (const float*)d_in[8];
  const float* advb  = (const float*)d_in[9];
  const float* v1w   = (const float*)d_in[10];
  const float* v1b   = (const float*)d_in[11];
  const float* v2w   = (const float*)d_in[12];
  const float* v2b   = (const float*)d_in[13];
  const float* v3w   = (const float*)d_in[14];
  const float* v3b   = (const float*)d_in[15];
  float* out = (float*)d_out;

  const size_t msgB  = (size_t)Nn * OUTC * 4;          // 128 KB
  const size_t wtB   = (size_t)Ktot * CTOT * 2;        // 16.8 MB
  const size_t featB = (size_t)Bsz * Ktot * 2;         // 67 MB

  int NS = 64;
  while (NS > 4 && msgB + wtB + featB + (size_t)NS * Bsz * CTOT * 4 > ws_size)
    NS >>= 1;
  bool mfma_ok = msgB + wtB + featB + (size_t)NS * Bsz * CTOT * 4 <= ws_size;

  float* msg = (float*)d_ws;
  setup_kernel<<<1, 256, 0, stream>>>(x, ei, w1, b1, w2, b2, msg);

  if (mfma_ok) {
    unsigned short* wtp   = (unsigned short*)((char*)d_ws + msgB);
    unsigned short* featp = (unsigned short*)((char*)d_ws + msgB + wtB);
    float* part = (float*)((char*)d_ws + msgB + wtB + featB);
    wt_kernel<<<1024, 256, 0, stream>>>(advw, v1w, wtp);
    feat_kernel<<<dim3(Nn, 8), 256, 0, stream>>>(x, rootw, convb, msg, featp);
    gemm_mfma<<<dim3(4, NS), 512, 0, stream>>>(featp, wtp, part, 1024 / NS);
    final_kernel<<<Bsz, 256, 0, stream>>>(part, NS, advb, v1b, v2w, v2b, v3w, v3b, out);
  } else {
    int NS2 = 64;
    while (NS2 > 1 && msgB + (size_t)NS2 * Bsz * CTOT * 4 > ws_size) NS2 >>= 1;
    float* part = msg + Nn * OUTC;
    int npc = Nn / NS2;
    gemm_f32<<<dim3(Bsz / BM, NS2), 256, 0, stream>>>(x, rootw, convb, advw, v1w, msg, part, npc);
    final_kernel<<<Bsz, 256, 0, stream>>>(part, NS2, advb, v1b, v2w, v2b, v3w, v3b, out);
  }
}